// Round 1
// baseline (776.965 us; speedup 1.0000x reference)
//
#include <hip/hip_runtime.h>
#include <hip/hip_bf16.h>

#define D 128
#define NEG 5
#define LR 0.025f
#define NCE_BIAS 11.512925464970229f      // log(100000)
#define NCE_NEG_BIAS 9.903487552536127f   // log(100000/5)
#define LUT_SIZE 1202

__device__ __forceinline__ float wave_allreduce(float x) {
    // 64-lane butterfly; every lane ends with the full sum
    #pragma unroll
    for (int m = 32; m >= 1; m >>= 1) x += __shfl_xor(x, m, 64);
    return x;
}

__device__ __forceinline__ float fast_sig(float s, const float* __restrict__ lut) {
    s = fminf(fmaxf(s, -6.0f), 6.0f);
    int idx = (int)floorf((s + 6.01f) / 0.01f);
    idx = min(max(idx, 0), LUT_SIZE - 1);
    return lut[idx];
}

// One wave per positive pair. Gather from pristine Worig, scatter-add to W.
__global__ __launch_bounds__(256) void pos_kernel(
    const float* __restrict__ Worig, float* __restrict__ W,
    const float* __restrict__ lut,
    const int* __restrict__ idx_u, const int* __restrict__ idx_v, int n)
{
    int wave = (int)((blockIdx.x * blockDim.x + threadIdx.x) >> 6);
    int lane = threadIdx.x & 63;
    if (wave >= n) return;
    int u = idx_u[wave];
    int v = idx_v[wave];
    const float2* pu = (const float2*)(Worig + (size_t)u * D);
    const float2* pv = (const float2*)(Worig + (size_t)v * D);
    float2 eu = pu[lane];
    float2 ev = pv[lane];
    float dot = wave_allreduce(eu.x * ev.x + eu.y * ev.y);
    float s = (1.0f - fast_sig(dot - NCE_BIAS, lut)) * LR;
    float* wu = W + (size_t)u * D;
    float* wv = W + (size_t)v * D;
    atomicAdd(&wu[2 * lane],     s * ev.x);
    atomicAdd(&wu[2 * lane + 1], s * ev.y);
    atomicAdd(&wv[2 * lane],     s * eu.x);
    atomicAdd(&wv[2 * lane + 1], s * eu.y);
}

// One wave per node: handles its NEG=5 negative pairs (idx_neg_u = repeat(idx_pos_u, 5)).
// Gather from the W_pos snapshot; accumulate u-update in registers (one atomic row-add).
__global__ __launch_bounds__(256) void neg_kernel(
    const float* __restrict__ Wsnap, float* __restrict__ W,
    const float* __restrict__ lut,
    const int* __restrict__ idx_u, const int* __restrict__ idx_v, int n)
{
    int wave = (int)((blockIdx.x * blockDim.x + threadIdx.x) >> 6);
    int lane = threadIdx.x & 63;
    if (wave >= n) return;
    int u = idx_u[wave * NEG];  // same u for all 5 negatives of this node
    const float2* pu = (const float2*)(Wsnap + (size_t)u * D);
    float2 eu = pu[lane];
    float dux = 0.0f, duy = 0.0f;
    #pragma unroll
    for (int j = 0; j < NEG; ++j) {
        int v = idx_v[wave * NEG + j];
        const float2* pv = (const float2*)(Wsnap + (size_t)v * D);
        float2 ev = pv[lane];
        float dot = wave_allreduce(eu.x * ev.x + eu.y * ev.y);
        float s = -fast_sig(dot - NCE_NEG_BIAS, lut) * LR;
        dux += s * ev.x;
        duy += s * ev.y;
        float* wv = W + (size_t)v * D;
        atomicAdd(&wv[2 * lane],     s * eu.x);
        atomicAdd(&wv[2 * lane + 1], s * eu.y);
    }
    float* wu = W + (size_t)u * D;
    atomicAdd(&wu[2 * lane],     dux);
    atomicAdd(&wu[2 * lane + 1], duy);
}

extern "C" void kernel_launch(void* const* d_in, const int* in_sizes, int n_in,
                              void* d_out, int out_size, void* d_ws, size_t ws_size,
                              hipStream_t stream) {
    const float* W    = (const float*)d_in[0];
    const float* lut  = (const float*)d_in[1];
    const int* ipu    = (const int*)d_in[2];
    const int* ipv    = (const int*)d_in[3];
    const int* inu    = (const int*)d_in[4];
    const int* inv    = (const int*)d_in[5];
    float* out  = (float*)d_out;
    float* snap = (float*)d_ws;

    const int N = in_sizes[2];                      // 100000 nodes / positive pairs
    const size_t WB = (size_t)N * D * sizeof(float);

    // W -> out (working copy)
    hipMemcpyAsync(out, W, WB, hipMemcpyDeviceToDevice, stream);

    // positive phase: gather pristine W, scatter-add into out
    const int waves_per_block = 4;                  // 256 threads
    int blocks = (N + waves_per_block - 1) / waves_per_block;
    pos_kernel<<<blocks, 256, 0, stream>>>(W, out, lut, ipu, ipv, N);

    // snapshot W_pos so negative gathers don't race negative scatters
    hipMemcpyAsync(snap, out, WB, hipMemcpyDeviceToDevice, stream);

    // negative phase: gather snapshot, scatter-add into out
    neg_kernel<<<blocks, 256, 0, stream>>>(snap, out, lut, inu, inv, N);
}

// Round 2
// 451.442 us; speedup vs baseline: 1.7211x; 1.7211x over previous
//
#include <hip/hip_runtime.h>
#include <hip/hip_bf16.h>

#define D 128
#define LR 0.025f
#define NCE_BIAS 11.512925464970229f      // log(100000)
#define NCE_NEG_BIAS 9.903487552536127f   // log(100000/5)
#define LUT_SIZE 1202

__device__ __forceinline__ float wave_allreduce(float x) {
    #pragma unroll
    for (int m = 32; m >= 1; m >>= 1) x += __shfl_xor(x, m, 64);
    return x;
}

__device__ __forceinline__ float fast_sig(float s, const float* __restrict__ lut) {
    s = fminf(fmaxf(s, -6.0f), 6.0f);
    int idx = (int)floorf((s + 6.01f) / 0.01f);
    idx = min(max(idx, 0), LUT_SIZE - 1);
    return lut[idx];
}

// ---------------- CSR build ----------------
// cnt[2*i]   = pos-degree of node i, cnt[2*i+1] = neg-degree of node i.

__global__ __launch_bounds__(256) void hist_kernel(
    const int* __restrict__ ipu, const int* __restrict__ ipv,
    const int* __restrict__ inu, const int* __restrict__ inv,
    int Np, int Nn, int* __restrict__ cnt)
{
    int t = blockIdx.x * 256 + threadIdx.x;
    if (t < Np) {
        atomicAdd(&cnt[2 * ipu[t]], 1);
        atomicAdd(&cnt[2 * ipv[t]], 1);
    } else if (t < Np + Nn) {
        int k = t - Np;
        atomicAdd(&cnt[2 * inu[k] + 1], 1);
        atomicAdd(&cnt[2 * inv[k] + 1], 1);
    }
}

// 3-kernel exclusive scan over n=2N counters
__global__ __launch_bounds__(256) void scan_local(
    const int* __restrict__ cnt, int* __restrict__ off, int* __restrict__ bsum, int n)
{
    __shared__ int sh[256];
    int g = blockIdx.x * 256 + threadIdx.x;
    int x = (g < n) ? cnt[g] : 0;
    sh[threadIdx.x] = x;
    __syncthreads();
    #pragma unroll
    for (int d = 1; d < 256; d <<= 1) {
        int t = (threadIdx.x >= d) ? sh[threadIdx.x - d] : 0;
        __syncthreads();
        sh[threadIdx.x] += t;
        __syncthreads();
    }
    if (g < n) off[g] = sh[threadIdx.x] - x;   // exclusive
    if (threadIdx.x == 255) bsum[blockIdx.x] = sh[255];
}

__global__ __launch_bounds__(256) void scan_bsum(int* __restrict__ bsum, int nb)
{
    __shared__ int sh[256];
    __shared__ int carry_s;
    if (threadIdx.x == 0) carry_s = 0;
    __syncthreads();
    for (int c = 0; c < nb; c += 256) {
        int i = c + threadIdx.x;
        int x = (i < nb) ? bsum[i] : 0;
        sh[threadIdx.x] = x;
        __syncthreads();
        for (int d = 1; d < 256; d <<= 1) {
            int t = (threadIdx.x >= d) ? sh[threadIdx.x - d] : 0;
            __syncthreads();
            sh[threadIdx.x] += t;
            __syncthreads();
        }
        int carry = carry_s;
        if (i < nb) bsum[i] = sh[threadIdx.x] - x + carry;
        __syncthreads();
        if (threadIdx.x == 0) carry_s = carry + sh[255];
        __syncthreads();
    }
}

__global__ __launch_bounds__(256) void add_base(
    int* __restrict__ off, int* __restrict__ cur, const int* __restrict__ bsum, int n)
{
    int g = blockIdx.x * 256 + threadIdx.x;
    if (g < n) {
        int v = off[g] + bsum[blockIdx.x];
        off[g] = v;
        cur[g] = v;
    }
}

// entries[slot] = partner node id (score is symmetric in (u,v) -> no side flag needed)
__global__ __launch_bounds__(256) void fill_kernel(
    const int* __restrict__ ipu, const int* __restrict__ ipv,
    const int* __restrict__ inu, const int* __restrict__ inv,
    int Np, int Nn, int* __restrict__ cur, int* __restrict__ entries)
{
    int t = blockIdx.x * 256 + threadIdx.x;
    if (t < Np) {
        int u = ipu[t], v = ipv[t];
        entries[atomicAdd(&cur[2 * u], 1)] = v;
        entries[atomicAdd(&cur[2 * v], 1)] = u;
    } else if (t < Np + Nn) {
        int k = t - Np;
        int u = inu[k], v = inv[k];
        entries[atomicAdd(&cur[2 * u + 1], 1)] = v;
        entries[atomicAdd(&cur[2 * v + 1], 1)] = u;
    }
}

// ---------------- pull update ----------------
// One wave per node: dst[i] = src[i] + sum_j s_j * src[partner_j]
// s_j = (c - sigmoid(dot(src[i], src[partner_j]) - bias)) * LR, c = 1 (pos) / 0 (neg).
// dot uses src rows only -> score identical to reference's phase semantics.
__global__ __launch_bounds__(256) void update_kernel(
    const float* __restrict__ src, float* __restrict__ dst,
    const float* __restrict__ lut,
    const int* __restrict__ off, const int* __restrict__ cnt,
    const int* __restrict__ entries,
    int N, int parity, float bias, float cpos)
{
    int wave = (int)((blockIdx.x * blockDim.x + threadIdx.x) >> 6);
    int lane = threadIdx.x & 63;
    if (wave >= N) return;

    const float2* prow = (const float2*)(src + (size_t)wave * D);
    float2 base = prow[lane];
    float ax = 0.0f, ay = 0.0f;

    int j = 2 * wave + parity;
    int beg = off[j];
    int len = cnt[j];

    // register double-buffer: prefetch next partner row during current reduce
    float2 pr = make_float2(0.0f, 0.0f);
    if (len > 0) {
        int p0 = entries[beg];
        pr = ((const float2*)(src + (size_t)p0 * D))[lane];
    }
    for (int t = 0; t < len; ++t) {
        float2 cpr = pr;
        if (t + 1 < len) {
            int pn = entries[beg + t + 1];
            pr = ((const float2*)(src + (size_t)pn * D))[lane];
        }
        float dot = wave_allreduce(base.x * cpr.x + base.y * cpr.y);
        float s = (cpos - fast_sig(dot - bias, lut)) * LR;
        ax += s * cpr.x;
        ay += s * cpr.y;
    }
    ((float2*)(dst + (size_t)wave * D))[lane] = make_float2(base.x + ax, base.y + ay);
}

// ---------------- fallback scatter path (round-1, known-good) ----------------
__global__ __launch_bounds__(256) void pos_kernel(
    const float* __restrict__ Worig, float* __restrict__ W,
    const float* __restrict__ lut,
    const int* __restrict__ idx_u, const int* __restrict__ idx_v, int n)
{
    int wave = (int)((blockIdx.x * blockDim.x + threadIdx.x) >> 6);
    int lane = threadIdx.x & 63;
    if (wave >= n) return;
    int u = idx_u[wave];
    int v = idx_v[wave];
    float2 eu = ((const float2*)(Worig + (size_t)u * D))[lane];
    float2 ev = ((const float2*)(Worig + (size_t)v * D))[lane];
    float dot = wave_allreduce(eu.x * ev.x + eu.y * ev.y);
    float s = (1.0f - fast_sig(dot - NCE_BIAS, lut)) * LR;
    float* wu = W + (size_t)u * D;
    float* wv = W + (size_t)v * D;
    atomicAdd(&wu[2 * lane],     s * ev.x);
    atomicAdd(&wu[2 * lane + 1], s * ev.y);
    atomicAdd(&wv[2 * lane],     s * eu.x);
    atomicAdd(&wv[2 * lane + 1], s * eu.y);
}

__global__ __launch_bounds__(256) void neg_kernel(
    const float* __restrict__ Wsnap, float* __restrict__ W,
    const float* __restrict__ lut,
    const int* __restrict__ idx_u, const int* __restrict__ idx_v, int n, int neg)
{
    int wave = (int)((blockIdx.x * blockDim.x + threadIdx.x) >> 6);
    int lane = threadIdx.x & 63;
    if (wave >= n) return;
    int u = idx_u[wave * neg];
    float2 eu = ((const float2*)(Wsnap + (size_t)u * D))[lane];
    float dux = 0.0f, duy = 0.0f;
    for (int j = 0; j < neg; ++j) {
        int v = idx_v[wave * neg + j];
        float2 ev = ((const float2*)(Wsnap + (size_t)v * D))[lane];
        float dot = wave_allreduce(eu.x * ev.x + eu.y * ev.y);
        float s = -fast_sig(dot - NCE_NEG_BIAS, lut) * LR;
        dux += s * ev.x;
        duy += s * ev.y;
        float* wv = W + (size_t)v * D;
        atomicAdd(&wv[2 * lane],     s * eu.x);
        atomicAdd(&wv[2 * lane + 1], s * eu.y);
    }
    float* wu = W + (size_t)u * D;
    atomicAdd(&wu[2 * lane],     dux);
    atomicAdd(&wu[2 * lane + 1], duy);
}

extern "C" void kernel_launch(void* const* d_in, const int* in_sizes, int n_in,
                              void* d_out, int out_size, void* d_ws, size_t ws_size,
                              hipStream_t stream) {
    const float* W   = (const float*)d_in[0];
    const float* lut = (const float*)d_in[1];
    const int* ipu   = (const int*)d_in[2];
    const int* ipv   = (const int*)d_in[3];
    const int* inu   = (const int*)d_in[4];
    const int* inv   = (const int*)d_in[5];
    float* out = (float*)d_out;

    const int N  = in_sizes[2];            // nodes == positive pairs
    const int Np = in_sizes[2];
    const int Nn = in_sizes[4];            // N * NEG
    const size_t WB = (size_t)N * D * sizeof(float);
    const int n2 = 2 * N;
    const int nb = (n2 + 255) / 256;
    const int nent = 2 * Np + 2 * Nn;

    size_t need = WB + (size_t)nent * 4 + (size_t)n2 * 4 * 3 + (size_t)nb * 4;

    if (ws_size >= need) {
        char* p = (char*)d_ws;
        float* Wpos   = (float*)p; p += WB;
        int* entries  = (int*)p;   p += (size_t)nent * 4;
        int* cnt      = (int*)p;   p += (size_t)n2 * 4;
        int* off      = (int*)p;   p += (size_t)n2 * 4;
        int* cur      = (int*)p;   p += (size_t)n2 * 4;
        int* bsum     = (int*)p;

        hipMemsetAsync(cnt, 0, (size_t)n2 * 4, stream);
        int tot = Np + Nn;
        hist_kernel<<<(tot + 255) / 256, 256, 0, stream>>>(ipu, ipv, inu, inv, Np, Nn, cnt);
        scan_local<<<nb, 256, 0, stream>>>(cnt, off, bsum, n2);
        scan_bsum<<<1, 256, 0, stream>>>(bsum, nb);
        add_base<<<nb, 256, 0, stream>>>(off, cur, bsum, n2);
        fill_kernel<<<(tot + 255) / 256, 256, 0, stream>>>(ipu, ipv, inu, inv, Np, Nn, cur, entries);

        int ublocks = (N * 64 + 255) / 256;   // one 64-lane wave per node
        update_kernel<<<ublocks, 256, 0, stream>>>(W,    Wpos, lut, off, cnt, entries, N, 0, NCE_BIAS,     1.0f);
        update_kernel<<<ublocks, 256, 0, stream>>>(Wpos, out,  lut, off, cnt, entries, N, 1, NCE_NEG_BIAS, 0.0f);
    } else {
        // scatter fallback (needs only one W-sized snapshot)
        float* snap = (float*)d_ws;
        const int neg = Nn / Np;
        hipMemcpyAsync(out, W, WB, hipMemcpyDeviceToDevice, stream);
        int blocks = (N * 64 + 255) / 256;
        pos_kernel<<<blocks, 256, 0, stream>>>(W, out, lut, ipu, ipv, N);
        hipMemcpyAsync(snap, out, WB, hipMemcpyDeviceToDevice, stream);
        neg_kernel<<<blocks, 256, 0, stream>>>(snap, out, lut, inu, inv, N, neg);
    }
}

// Round 3
// 405.764 us; speedup vs baseline: 1.9148x; 1.1126x over previous
//
#include <hip/hip_runtime.h>
#include <hip/hip_bf16.h>

#define D 128
#define LR 0.025f
#define NCE_BIAS 11.512925464970229f      // log(100000)
#define NCE_NEG_BIAS 9.903487552536127f   // log(100000/5)
#define LUT_SIZE 1202

__device__ __forceinline__ float wave_allreduce(float x) {
    #pragma unroll
    for (int m = 32; m >= 1; m >>= 1) x += __shfl_xor(x, m, 64);
    return x;
}

// Analytic stand-in for the reference's LUT sigmoid.
// LUT evaluates sigmoid at -6.01 + 0.01*floor((clip(x)+6.01)/0.01) which lies in
// (x-0.01, x]; shifting by -0.005 centers the quantization error (|err|<=1.25e-3).
__device__ __forceinline__ float fast_sig(float x) {
    x = fminf(fmaxf(x, -6.0f), 6.0f) - 0.005f;
    float e = __expf(-x);
    return __builtin_amdgcn_rcpf(1.0f + e);
}

__device__ __forceinline__ float fast_sig_lut(float s, const float* __restrict__ lut) {
    s = fminf(fmaxf(s, -6.0f), 6.0f);
    int idx = (int)floorf((s + 6.01f) / 0.01f);
    idx = min(max(idx, 0), LUT_SIZE - 1);
    return lut[idx];
}

// ---------------- CSR build ----------------
__global__ __launch_bounds__(256) void hist_kernel(
    const int* __restrict__ ipu, const int* __restrict__ ipv,
    const int* __restrict__ inu, const int* __restrict__ inv,
    int Np, int Nn, int* __restrict__ cnt)
{
    int t = blockIdx.x * 256 + threadIdx.x;
    if (t < Np) {
        atomicAdd(&cnt[2 * ipu[t]], 1);
        atomicAdd(&cnt[2 * ipv[t]], 1);
    } else if (t < Np + Nn) {
        int k = t - Np;
        atomicAdd(&cnt[2 * inu[k] + 1], 1);
        atomicAdd(&cnt[2 * inv[k] + 1], 1);
    }
}

__global__ __launch_bounds__(256) void scan_local(
    const int* __restrict__ cnt, int* __restrict__ off, int* __restrict__ bsum, int n)
{
    __shared__ int sh[256];
    int g = blockIdx.x * 256 + threadIdx.x;
    int x = (g < n) ? cnt[g] : 0;
    sh[threadIdx.x] = x;
    __syncthreads();
    #pragma unroll
    for (int d = 1; d < 256; d <<= 1) {
        int t = (threadIdx.x >= d) ? sh[threadIdx.x - d] : 0;
        __syncthreads();
        sh[threadIdx.x] += t;
        __syncthreads();
    }
    if (g < n) off[g] = sh[threadIdx.x] - x;   // exclusive
    if (threadIdx.x == 255) bsum[blockIdx.x] = sh[255];
}

__global__ __launch_bounds__(256) void scan_bsum(int* __restrict__ bsum, int nb)
{
    __shared__ int sh[256];
    __shared__ int carry_s;
    if (threadIdx.x == 0) carry_s = 0;
    __syncthreads();
    for (int c = 0; c < nb; c += 256) {
        int i = c + threadIdx.x;
        int x = (i < nb) ? bsum[i] : 0;
        sh[threadIdx.x] = x;
        __syncthreads();
        for (int d = 1; d < 256; d <<= 1) {
            int t = (threadIdx.x >= d) ? sh[threadIdx.x - d] : 0;
            __syncthreads();
            sh[threadIdx.x] += t;
            __syncthreads();
        }
        int carry = carry_s;
        if (i < nb) bsum[i] = sh[threadIdx.x] - x + carry;
        __syncthreads();
        if (threadIdx.x == 0) carry_s = carry + sh[255];
        __syncthreads();
    }
}

__global__ __launch_bounds__(256) void add_base(
    int* __restrict__ off, int* __restrict__ cur, const int* __restrict__ bsum, int n)
{
    int g = blockIdx.x * 256 + threadIdx.x;
    if (g < n) {
        int v = off[g] + bsum[blockIdx.x];
        off[g] = v;
        cur[g] = v;
    }
}

__global__ __launch_bounds__(256) void fill_kernel(
    const int* __restrict__ ipu, const int* __restrict__ ipv,
    const int* __restrict__ inu, const int* __restrict__ inv,
    int Np, int Nn, int* __restrict__ cur, int* __restrict__ entries)
{
    int t = blockIdx.x * 256 + threadIdx.x;
    if (t < Np) {
        int u = ipu[t], v = ipv[t];
        entries[atomicAdd(&cur[2 * u], 1)] = v;
        entries[atomicAdd(&cur[2 * v], 1)] = u;
    } else if (t < Np + Nn) {
        int k = t - Np;
        int u = inu[k], v = inv[k];
        entries[atomicAdd(&cur[2 * u + 1], 1)] = v;
        entries[atomicAdd(&cur[2 * v + 1], 1)] = u;
    }
}

// ---------------- pull update ----------------
// One wave per node: dst[i] = src[i] + sum_j s_j * src[partner_j].
// 4-wide partner batching: 4 row gathers in flight, 4 interleaved butterfly
// reduction chains, analytic sigmoid (no dependent LUT load on critical path).
__global__ __launch_bounds__(256) void update_kernel(
    const float* __restrict__ src, float* __restrict__ dst,
    const int* __restrict__ off, const int* __restrict__ cnt,
    const int* __restrict__ entries,
    int N, int parity, float bias, float cpos)
{
    int wave = (int)((blockIdx.x * blockDim.x + threadIdx.x) >> 6);
    int lane = threadIdx.x & 63;
    if (wave >= N) return;

    const float2* srcv = (const float2*)src;
    float2 base = srcv[(size_t)wave * 64 + lane];
    float ax = 0.0f, ay = 0.0f;

    int j = 2 * wave + parity;
    int beg = off[j];
    int len = cnt[j];

    for (int g = 0; g < len; g += 4) {
        float2 r[4];
        float d[4];
        #pragma unroll
        for (int i = 0; i < 4; ++i) {
            int t = g + i;
            int p = (t < len) ? entries[beg + t] : wave;  // inactive -> own row (L1 hit)
            r[i] = srcv[(size_t)p * 64 + lane];
        }
        #pragma unroll
        for (int i = 0; i < 4; ++i) d[i] = r[i].x * base.x + r[i].y * base.y;
        #pragma unroll
        for (int m = 32; m >= 1; m >>= 1) {
            #pragma unroll
            for (int i = 0; i < 4; ++i) d[i] += __shfl_xor(d[i], m, 64);
        }
        #pragma unroll
        for (int i = 0; i < 4; ++i) {
            float s = (g + i < len) ? (cpos - fast_sig(d[i] - bias)) * LR : 0.0f;
            ax += s * r[i].x;
            ay += s * r[i].y;
        }
    }
    ((float2*)dst)[(size_t)wave * 64 + lane] = make_float2(base.x + ax, base.y + ay);
}

// ---------------- fallback scatter path (round-1, known-good) ----------------
__global__ __launch_bounds__(256) void pos_kernel(
    const float* __restrict__ Worig, float* __restrict__ W,
    const float* __restrict__ lut,
    const int* __restrict__ idx_u, const int* __restrict__ idx_v, int n)
{
    int wave = (int)((blockIdx.x * blockDim.x + threadIdx.x) >> 6);
    int lane = threadIdx.x & 63;
    if (wave >= n) return;
    int u = idx_u[wave];
    int v = idx_v[wave];
    float2 eu = ((const float2*)(Worig + (size_t)u * D))[lane];
    float2 ev = ((const float2*)(Worig + (size_t)v * D))[lane];
    float dot = wave_allreduce(eu.x * ev.x + eu.y * ev.y);
    float s = (1.0f - fast_sig_lut(dot - NCE_BIAS, lut)) * LR;
    float* wu = W + (size_t)u * D;
    float* wv = W + (size_t)v * D;
    atomicAdd(&wu[2 * lane],     s * ev.x);
    atomicAdd(&wu[2 * lane + 1], s * ev.y);
    atomicAdd(&wv[2 * lane],     s * eu.x);
    atomicAdd(&wv[2 * lane + 1], s * eu.y);
}

__global__ __launch_bounds__(256) void neg_kernel(
    const float* __restrict__ Wsnap, float* __restrict__ W,
    const float* __restrict__ lut,
    const int* __restrict__ idx_u, const int* __restrict__ idx_v, int n, int neg)
{
    int wave = (int)((blockIdx.x * blockDim.x + threadIdx.x) >> 6);
    int lane = threadIdx.x & 63;
    if (wave >= n) return;
    int u = idx_u[wave * neg];
    float2 eu = ((const float2*)(Wsnap + (size_t)u * D))[lane];
    float dux = 0.0f, duy = 0.0f;
    for (int j = 0; j < neg; ++j) {
        int v = idx_v[wave * neg + j];
        float2 ev = ((const float2*)(Wsnap + (size_t)v * D))[lane];
        float dot = wave_allreduce(eu.x * ev.x + eu.y * ev.y);
        float s = -fast_sig_lut(dot - NCE_NEG_BIAS, lut) * LR;
        dux += s * ev.x;
        duy += s * ev.y;
        float* wv = W + (size_t)v * D;
        atomicAdd(&wv[2 * lane],     s * eu.x);
        atomicAdd(&wv[2 * lane + 1], s * eu.y);
    }
    float* wu = W + (size_t)u * D;
    atomicAdd(&wu[2 * lane],     dux);
    atomicAdd(&wu[2 * lane + 1], duy);
}

extern "C" void kernel_launch(void* const* d_in, const int* in_sizes, int n_in,
                              void* d_out, int out_size, void* d_ws, size_t ws_size,
                              hipStream_t stream) {
    const float* W   = (const float*)d_in[0];
    const float* lut = (const float*)d_in[1];
    const int* ipu   = (const int*)d_in[2];
    const int* ipv   = (const int*)d_in[3];
    const int* inu   = (const int*)d_in[4];
    const int* inv   = (const int*)d_in[5];
    float* out = (float*)d_out;

    const int N  = in_sizes[2];            // nodes == positive pairs
    const int Np = in_sizes[2];
    const int Nn = in_sizes[4];            // N * NEG
    const size_t WB = (size_t)N * D * sizeof(float);
    const int n2 = 2 * N;
    const int nb = (n2 + 255) / 256;
    const int nent = 2 * Np + 2 * Nn;

    size_t need = WB + (size_t)nent * 4 + (size_t)n2 * 4 * 3 + (size_t)nb * 4;

    if (ws_size >= need) {
        char* p = (char*)d_ws;
        float* Wpos   = (float*)p; p += WB;
        int* entries  = (int*)p;   p += (size_t)nent * 4;
        int* cnt      = (int*)p;   p += (size_t)n2 * 4;
        int* off      = (int*)p;   p += (size_t)n2 * 4;
        int* cur      = (int*)p;   p += (size_t)n2 * 4;
        int* bsum     = (int*)p;

        hipMemsetAsync(cnt, 0, (size_t)n2 * 4, stream);
        int tot = Np + Nn;
        hist_kernel<<<(tot + 255) / 256, 256, 0, stream>>>(ipu, ipv, inu, inv, Np, Nn, cnt);
        scan_local<<<nb, 256, 0, stream>>>(cnt, off, bsum, n2);
        scan_bsum<<<1, 256, 0, stream>>>(bsum, nb);
        add_base<<<nb, 256, 0, stream>>>(off, cur, bsum, n2);
        fill_kernel<<<(tot + 255) / 256, 256, 0, stream>>>(ipu, ipv, inu, inv, Np, Nn, cur, entries);

        int ublocks = (N * 64 + 255) / 256;   // one 64-lane wave per node
        update_kernel<<<ublocks, 256, 0, stream>>>(W,    Wpos, off, cnt, entries, N, 0, NCE_BIAS,     1.0f);
        update_kernel<<<ublocks, 256, 0, stream>>>(Wpos, out,  off, cnt, entries, N, 1, NCE_NEG_BIAS, 0.0f);
    } else {
        // scatter fallback (needs only one W-sized snapshot)
        float* snap = (float*)d_ws;
        const int neg = Nn / Np;
        hipMemcpyAsync(out, W, WB, hipMemcpyDeviceToDevice, stream);
        int blocks = (N * 64 + 255) / 256;
        pos_kernel<<<blocks, 256, 0, stream>>>(W, out, lut, ipu, ipv, N);
        hipMemcpyAsync(snap, out, WB, hipMemcpyDeviceToDevice, stream);
        neg_kernel<<<blocks, 256, 0, stream>>>(snap, out, lut, inu, inv, N, neg);
    }
}

// Round 4
// 364.199 us; speedup vs baseline: 2.1333x; 1.1141x over previous
//
#include <hip/hip_runtime.h>
#include <hip/hip_bf16.h>

#define D 128
#define LR 0.025f
#define NCE_BIAS 11.512925464970229f      // log(100000)
#define NCE_NEG_BIAS 9.903487552536127f   // log(100000/5)
#define LUT_SIZE 1202

__device__ __forceinline__ float wave_allreduce(float x) {
    #pragma unroll
    for (int m = 32; m >= 1; m >>= 1) x += __shfl_xor(x, m, 64);
    return x;
}

// Analytic stand-in for the reference's LUT sigmoid.
// LUT evaluates sigmoid at -6.01 + 0.01*floor((clip(x)+6.01)/0.01) which lies in
// (x-0.01, x]; shifting by -0.005 centers the quantization error (|err|<=1.25e-3).
__device__ __forceinline__ float fast_sig(float x) {
    x = fminf(fmaxf(x, -6.0f), 6.0f) - 0.005f;
    float e = __expf(-x);
    return __builtin_amdgcn_rcpf(1.0f + e);
}

__device__ __forceinline__ float fast_sig_lut(float s, const float* __restrict__ lut) {
    s = fminf(fmaxf(s, -6.0f), 6.0f);
    int idx = (int)floorf((s + 6.01f) / 0.01f);
    idx = min(max(idx, 0), LUT_SIZE - 1);
    return lut[idx];
}

// ---------------- CSR build ----------------
__global__ __launch_bounds__(256) void hist_kernel(
    const int* __restrict__ ipu, const int* __restrict__ ipv,
    const int* __restrict__ inu, const int* __restrict__ inv,
    int Np, int Nn, int* __restrict__ cnt)
{
    int t = blockIdx.x * 256 + threadIdx.x;
    if (t < Np) {
        atomicAdd(&cnt[2 * ipu[t]], 1);
        atomicAdd(&cnt[2 * ipv[t]], 1);
    } else if (t < Np + Nn) {
        int k = t - Np;
        atomicAdd(&cnt[2 * inu[k] + 1], 1);
        atomicAdd(&cnt[2 * inv[k] + 1], 1);
    }
}

__global__ __launch_bounds__(256) void scan_local(
    const int* __restrict__ cnt, int* __restrict__ off, int* __restrict__ bsum, int n)
{
    __shared__ int sh[256];
    int g = blockIdx.x * 256 + threadIdx.x;
    int x = (g < n) ? cnt[g] : 0;
    sh[threadIdx.x] = x;
    __syncthreads();
    #pragma unroll
    for (int d = 1; d < 256; d <<= 1) {
        int t = (threadIdx.x >= d) ? sh[threadIdx.x - d] : 0;
        __syncthreads();
        sh[threadIdx.x] += t;
        __syncthreads();
    }
    if (g < n) off[g] = sh[threadIdx.x] - x;   // exclusive
    if (threadIdx.x == 255) bsum[blockIdx.x] = sh[255];
}

__global__ __launch_bounds__(256) void scan_bsum(int* __restrict__ bsum, int nb)
{
    __shared__ int sh[256];
    __shared__ int carry_s;
    if (threadIdx.x == 0) carry_s = 0;
    __syncthreads();
    for (int c = 0; c < nb; c += 256) {
        int i = c + threadIdx.x;
        int x = (i < nb) ? bsum[i] : 0;
        sh[threadIdx.x] = x;
        __syncthreads();
        for (int d = 1; d < 256; d <<= 1) {
            int t = (threadIdx.x >= d) ? sh[threadIdx.x - d] : 0;
            __syncthreads();
            sh[threadIdx.x] += t;
            __syncthreads();
        }
        int carry = carry_s;
        if (i < nb) bsum[i] = sh[threadIdx.x] - x + carry;
        __syncthreads();
        if (threadIdx.x == 0) carry_s = carry + sh[255];
        __syncthreads();
    }
}

__global__ __launch_bounds__(256) void add_base(
    int* __restrict__ off, int* __restrict__ cur, const int* __restrict__ bsum, int n)
{
    int g = blockIdx.x * 256 + threadIdx.x;
    if (g < n) {
        int v = off[g] + bsum[blockIdx.x];
        off[g] = v;
        cur[g] = v;
    }
}

__global__ __launch_bounds__(256) void fill_kernel(
    const int* __restrict__ ipu, const int* __restrict__ ipv,
    const int* __restrict__ inu, const int* __restrict__ inv,
    int Np, int Nn, int* __restrict__ cur, int* __restrict__ entries)
{
    int t = blockIdx.x * 256 + threadIdx.x;
    if (t < Np) {
        int u = ipu[t], v = ipv[t];
        entries[atomicAdd(&cur[2 * u], 1)] = v;
        entries[atomicAdd(&cur[2 * v], 1)] = u;
    } else if (t < Np + Nn) {
        int k = t - Np;
        int u = inu[k], v = inv[k];
        entries[atomicAdd(&cur[2 * u + 1], 1)] = v;
        entries[atomicAdd(&cur[2 * v + 1], 1)] = u;
    }
}

// ---------------- pull update ----------------
// Half-wave per node (32 lanes x float4 = one 512B row per dwordx4).
// 2 nodes/wave, 4 partner rows in flight per half (8 per wave), 5-step
// butterfly within each half (xor masks <=16 never cross the 32-lane boundary).
__global__ __launch_bounds__(256) void update_kernel(
    const float* __restrict__ src, float* __restrict__ dst,
    const int* __restrict__ off, const int* __restrict__ cnt,
    const int* __restrict__ entries,
    int N, int parity, float bias, float cpos)
{
    int gtid = blockIdx.x * 256 + threadIdx.x;
    int node = gtid >> 5;                 // one node per 32-lane half-wave
    int hl   = threadIdx.x & 31;          // lane within half
    if (node >= N) return;

    const float4* srcv = (const float4*)src;
    float4 base = srcv[(size_t)node * 32 + hl];
    float ax = 0.0f, ay = 0.0f, az = 0.0f, aw = 0.0f;

    int j = 2 * node + parity;
    int beg = off[j];
    int len = cnt[j];

    for (int g = 0; g < len; g += 4) {
        float4 r[4];
        float d[4];
        #pragma unroll
        for (int i = 0; i < 4; ++i) {
            int t = g + i;
            int p = (t < len) ? entries[beg + t] : node;  // inactive -> own row (cache hit)
            r[i] = srcv[(size_t)p * 32 + hl];
        }
        #pragma unroll
        for (int i = 0; i < 4; ++i)
            d[i] = r[i].x * base.x + r[i].y * base.y + r[i].z * base.z + r[i].w * base.w;
        #pragma unroll
        for (int m = 16; m >= 1; m >>= 1) {
            #pragma unroll
            for (int i = 0; i < 4; ++i) d[i] += __shfl_xor(d[i], m, 64);
        }
        #pragma unroll
        for (int i = 0; i < 4; ++i) {
            float s = (g + i < len) ? (cpos - fast_sig(d[i] - bias)) * LR : 0.0f;
            ax += s * r[i].x;
            ay += s * r[i].y;
            az += s * r[i].z;
            aw += s * r[i].w;
        }
    }
    ((float4*)dst)[(size_t)node * 32 + hl] =
        make_float4(base.x + ax, base.y + ay, base.z + az, base.w + aw);
}

// ---------------- fallback scatter path (round-1, known-good) ----------------
__global__ __launch_bounds__(256) void pos_kernel(
    const float* __restrict__ Worig, float* __restrict__ W,
    const float* __restrict__ lut,
    const int* __restrict__ idx_u, const int* __restrict__ idx_v, int n)
{
    int wave = (int)((blockIdx.x * blockDim.x + threadIdx.x) >> 6);
    int lane = threadIdx.x & 63;
    if (wave >= n) return;
    int u = idx_u[wave];
    int v = idx_v[wave];
    float2 eu = ((const float2*)(Worig + (size_t)u * D))[lane];
    float2 ev = ((const float2*)(Worig + (size_t)v * D))[lane];
    float dot = wave_allreduce(eu.x * ev.x + eu.y * ev.y);
    float s = (1.0f - fast_sig_lut(dot - NCE_BIAS, lut)) * LR;
    float* wu = W + (size_t)u * D;
    float* wv = W + (size_t)v * D;
    atomicAdd(&wu[2 * lane],     s * ev.x);
    atomicAdd(&wu[2 * lane + 1], s * ev.y);
    atomicAdd(&wv[2 * lane],     s * eu.x);
    atomicAdd(&wv[2 * lane + 1], s * eu.y);
}

__global__ __launch_bounds__(256) void neg_kernel(
    const float* __restrict__ Wsnap, float* __restrict__ W,
    const float* __restrict__ lut,
    const int* __restrict__ idx_u, const int* __restrict__ idx_v, int n, int neg)
{
    int wave = (int)((blockIdx.x * blockDim.x + threadIdx.x) >> 6);
    int lane = threadIdx.x & 63;
    if (wave >= n) return;
    int u = idx_u[wave * neg];
    float2 eu = ((const float2*)(Wsnap + (size_t)u * D))[lane];
    float dux = 0.0f, duy = 0.0f;
    for (int j = 0; j < neg; ++j) {
        int v = idx_v[wave * neg + j];
        float2 ev = ((const float2*)(Wsnap + (size_t)v * D))[lane];
        float dot = wave_allreduce(eu.x * ev.x + eu.y * ev.y);
        float s = -fast_sig_lut(dot - NCE_NEG_BIAS, lut) * LR;
        dux += s * ev.x;
        duy += s * ev.y;
        float* wv = W + (size_t)v * D;
        atomicAdd(&wv[2 * lane],     s * eu.x);
        atomicAdd(&wv[2 * lane + 1], s * eu.y);
    }
    float* wu = W + (size_t)u * D;
    atomicAdd(&wu[2 * lane],     dux);
    atomicAdd(&wu[2 * lane + 1], duy);
}

extern "C" void kernel_launch(void* const* d_in, const int* in_sizes, int n_in,
                              void* d_out, int out_size, void* d_ws, size_t ws_size,
                              hipStream_t stream) {
    const float* W   = (const float*)d_in[0];
    const float* lut = (const float*)d_in[1];
    const int* ipu   = (const int*)d_in[2];
    const int* ipv   = (const int*)d_in[3];
    const int* inu   = (const int*)d_in[4];
    const int* inv   = (const int*)d_in[5];
    float* out = (float*)d_out;

    const int N  = in_sizes[2];            // nodes == positive pairs
    const int Np = in_sizes[2];
    const int Nn = in_sizes[4];            // N * NEG
    const size_t WB = (size_t)N * D * sizeof(float);
    const int n2 = 2 * N;
    const int nb = (n2 + 255) / 256;
    const int nent = 2 * Np + 2 * Nn;

    size_t need = WB + (size_t)nent * 4 + (size_t)n2 * 4 * 3 + (size_t)nb * 4;

    if (ws_size >= need) {
        char* p = (char*)d_ws;
        float* Wpos   = (float*)p; p += WB;
        int* entries  = (int*)p;   p += (size_t)nent * 4;
        int* cnt      = (int*)p;   p += (size_t)n2 * 4;
        int* off      = (int*)p;   p += (size_t)n2 * 4;
        int* cur      = (int*)p;   p += (size_t)n2 * 4;
        int* bsum     = (int*)p;

        hipMemsetAsync(cnt, 0, (size_t)n2 * 4, stream);
        int tot = Np + Nn;
        hist_kernel<<<(tot + 255) / 256, 256, 0, stream>>>(ipu, ipv, inu, inv, Np, Nn, cnt);
        scan_local<<<nb, 256, 0, stream>>>(cnt, off, bsum, n2);
        scan_bsum<<<1, 256, 0, stream>>>(bsum, nb);
        add_base<<<nb, 256, 0, stream>>>(off, cur, bsum, n2);
        fill_kernel<<<(tot + 255) / 256, 256, 0, stream>>>(ipu, ipv, inu, inv, Np, Nn, cur, entries);

        int ublocks = (N * 32 + 255) / 256;   // one 32-lane half-wave per node
        update_kernel<<<ublocks, 256, 0, stream>>>(W,    Wpos, off, cnt, entries, N, 0, NCE_BIAS,     1.0f);
        update_kernel<<<ublocks, 256, 0, stream>>>(Wpos, out,  off, cnt, entries, N, 1, NCE_NEG_BIAS, 0.0f);
    } else {
        // scatter fallback (needs only one W-sized snapshot)
        float* snap = (float*)d_ws;
        const int neg = Nn / Np;
        hipMemcpyAsync(out, W, WB, hipMemcpyDeviceToDevice, stream);
        int blocks = (N * 64 + 255) / 256;
        pos_kernel<<<blocks, 256, 0, stream>>>(W, out, lut, ipu, ipv, N);
        hipMemcpyAsync(snap, out, WB, hipMemcpyDeviceToDevice, stream);
        neg_kernel<<<blocks, 256, 0, stream>>>(snap, out, lut, inu, inv, N, neg);
    }
}

// Round 5
// 312.460 us; speedup vs baseline: 2.4866x; 1.1656x over previous
//
#include <hip/hip_runtime.h>
#include <hip/hip_bf16.h>

#define D 128
#define LR 0.025f
#define NCE_BIAS 11.512925464970229f      // log(100000)
#define NCE_NEG_BIAS 9.903487552536127f   // log(100000/5)
#define LUT_SIZE 1202

__device__ __forceinline__ float wave_allreduce(float x) {
    #pragma unroll
    for (int m = 32; m >= 1; m >>= 1) x += __shfl_xor(x, m, 64);
    return x;
}

// Analytic stand-in for the reference's LUT sigmoid (centered quantization err <=1.25e-3).
__device__ __forceinline__ float fast_sig(float x) {
    x = fminf(fmaxf(x, -6.0f), 6.0f) - 0.005f;
    float e = __expf(-x);
    return __builtin_amdgcn_rcpf(1.0f + e);
}

__device__ __forceinline__ float fast_sig_lut(float s, const float* __restrict__ lut) {
    s = fminf(fmaxf(s, -6.0f), 6.0f);
    int idx = (int)floorf((s + 6.01f) / 0.01f);
    idx = min(max(idx, 0), LUT_SIZE - 1);
    return lut[idx];
}

__device__ __forceinline__ unsigned int bf16_rne(float f) {
    unsigned int u = __float_as_uint(f);
    return (u + 0x7FFFu + ((u >> 16) & 1u)) >> 16;
}

// ---------------- CSR build (packed counters: low16 = pos-degree, high16 = neg-degree) ----------------
// neg-u side exploits idx_neg_u = repeat(idx_pos_u, NEG): one +NEG atomic reserves
// NEG contiguous slots; partners inv[NEG*t..] written contiguously.
__global__ __launch_bounds__(256) void hist_kernel(
    const int* __restrict__ ipu, const int* __restrict__ ipv,
    const int* __restrict__ inu, const int* __restrict__ inv,
    int Np, int Nn, int NEG, int* __restrict__ cnt)
{
    int t = blockIdx.x * 256 + threadIdx.x;
    if (t < Np) {
        int u = inu[(size_t)NEG * t];   // == ipu[t] (repeat structure)
        atomicAdd(&cnt[u], 1 + (NEG << 16));   // pos +1, neg +NEG in one beat
        atomicAdd(&cnt[ipu[t]], 0);            // no-op placeholder removed below
    } else if (t < Np + Nn) {
        int k = t - Np;
        atomicAdd(&cnt[inv[k]], 1 << 16);
    }
}

// NOTE: hist above handles the u endpoint; the v endpoint of pos pairs needs +1 too.
// Done in a single kernel to keep one pass:
__global__ __launch_bounds__(256) void hist_kernel2(
    const int* __restrict__ ipv, int Np, int* __restrict__ cnt)
{
    int t = blockIdx.x * 256 + threadIdx.x;
    if (t < Np) atomicAdd(&cnt[ipv[t]], 1);
}

// exclusive scan over (cnt[i]>>shift)&0xffff
__global__ __launch_bounds__(256) void scan_local(
    const int* __restrict__ cnt, int* __restrict__ off, int* __restrict__ bsum,
    int n, int shift)
{
    __shared__ int sh[256];
    int g = blockIdx.x * 256 + threadIdx.x;
    int x = (g < n) ? ((cnt[g] >> shift) & 0xFFFF) : 0;
    sh[threadIdx.x] = x;
    __syncthreads();
    #pragma unroll
    for (int d = 1; d < 256; d <<= 1) {
        int t = (threadIdx.x >= d) ? sh[threadIdx.x - d] : 0;
        __syncthreads();
        sh[threadIdx.x] += t;
        __syncthreads();
    }
    if (g < n) off[g] = sh[threadIdx.x] - x;   // exclusive
    if (threadIdx.x == 255) bsum[blockIdx.x] = sh[255];
}

__global__ __launch_bounds__(256) void scan_bsum(int* __restrict__ bsum, int nb)
{
    __shared__ int sh[256];
    __shared__ int carry_s;
    if (threadIdx.x == 0) carry_s = 0;
    __syncthreads();
    for (int c = 0; c < nb; c += 256) {
        int i = c + threadIdx.x;
        int x = (i < nb) ? bsum[i] : 0;
        sh[threadIdx.x] = x;
        __syncthreads();
        for (int d = 1; d < 256; d <<= 1) {
            int t = (threadIdx.x >= d) ? sh[threadIdx.x - d] : 0;
            __syncthreads();
            sh[threadIdx.x] += t;
            __syncthreads();
        }
        int carry = carry_s;
        if (i < nb) bsum[i] = sh[threadIdx.x] - x + carry;
        __syncthreads();
        if (threadIdx.x == 0) carry_s = carry + sh[255];
        __syncthreads();
    }
}

__global__ __launch_bounds__(256) void add_base(
    int* __restrict__ off, int* __restrict__ cur, const int* __restrict__ bsum, int n)
{
    int g = blockIdx.x * 256 + threadIdx.x;
    if (g < n) {
        int v = off[g] + bsum[blockIdx.x];
        off[g] = v;
        cur[g] = v;
    }
}

__global__ __launch_bounds__(256) void fill_kernel(
    const int* __restrict__ ipu, const int* __restrict__ ipv,
    const int* __restrict__ inu, const int* __restrict__ inv,
    int Np, int Nn, int NEG,
    int* __restrict__ cur_p, int* __restrict__ cur_n,
    int* __restrict__ ent_p, int* __restrict__ ent_n)
{
    int t = blockIdx.x * 256 + threadIdx.x;
    if (t < Np) {
        int u = ipu[t], v = ipv[t];
        ent_p[atomicAdd(&cur_p[u], 1)] = v;
        ent_p[atomicAdd(&cur_p[v], 1)] = u;
        int un = inu[(size_t)NEG * t];                 // == u (repeat structure)
        int ns = atomicAdd(&cur_n[un], NEG);
        for (int j = 0; j < NEG; ++j)
            ent_n[ns + j] = inv[(size_t)NEG * t + j];  // contiguous writes
    } else if (t < Np + Nn) {
        int k = t - Np;
        ent_n[atomicAdd(&cur_n[inv[k]], 1)] = inu[k];
    }
}

// ---------------- pull update ----------------
// Half-wave per node (32 lanes x float4). 4 partner rows in flight.
// BF16P: partner rows are bf16 (256B). EMIT16: also store bf16 shadow of output row.
template<bool BF16P, bool EMIT16>
__global__ __launch_bounds__(256) void update_kernel(
    const float* __restrict__ baseSrc,
    const float* __restrict__ partnerF,
    const unsigned short* __restrict__ partnerH,
    float* __restrict__ dst,
    unsigned short* __restrict__ dst16,
    const int* __restrict__ off, const int* __restrict__ cur,
    const int* __restrict__ entries,
    int N, float bias, float cpos)
{
    int gtid = blockIdx.x * 256 + threadIdx.x;
    int node = gtid >> 5;
    int hl   = threadIdx.x & 31;
    if (node >= N) return;

    float4 base = ((const float4*)baseSrc)[(size_t)node * 32 + hl];
    float ax = 0.0f, ay = 0.0f, az = 0.0f, aw = 0.0f;

    int beg = off[node];
    int len = cur[node] - beg;   // cur = off + cnt after fill

    for (int g = 0; g < len; g += 4) {
        float4 r[4];
        float d[4];
        #pragma unroll
        for (int i = 0; i < 4; ++i) {
            int t = g + i;
            int p = (t < len) ? entries[beg + t] : node;  // inactive -> own row (cache hit)
            if (BF16P) {
                uint2 raw = ((const uint2*)partnerH)[(size_t)p * 32 + hl];
                r[i].x = __uint_as_float(raw.x << 16);
                r[i].y = __uint_as_float(raw.x & 0xFFFF0000u);
                r[i].z = __uint_as_float(raw.y << 16);
                r[i].w = __uint_as_float(raw.y & 0xFFFF0000u);
            } else {
                r[i] = ((const float4*)partnerF)[(size_t)p * 32 + hl];
            }
        }
        #pragma unroll
        for (int i = 0; i < 4; ++i)
            d[i] = r[i].x * base.x + r[i].y * base.y + r[i].z * base.z + r[i].w * base.w;
        #pragma unroll
        for (int m = 16; m >= 1; m >>= 1) {
            #pragma unroll
            for (int i = 0; i < 4; ++i) d[i] += __shfl_xor(d[i], m, 64);
        }
        #pragma unroll
        for (int i = 0; i < 4; ++i) {
            float s = (g + i < len) ? (cpos - fast_sig(d[i] - bias)) * LR : 0.0f;
            ax += s * r[i].x;
            ay += s * r[i].y;
            az += s * r[i].z;
            aw += s * r[i].w;
        }
    }
    float4 o = make_float4(base.x + ax, base.y + ay, base.z + az, base.w + aw);
    ((float4*)dst)[(size_t)node * 32 + hl] = o;
    if (EMIT16) {
        uint2 h;
        h.x = bf16_rne(o.x) | (bf16_rne(o.y) << 16);
        h.y = bf16_rne(o.z) | (bf16_rne(o.w) << 16);
        ((uint2*)dst16)[(size_t)node * 32 + hl] = h;
    }
}

// ---------------- fallback scatter path (round-1, known-good) ----------------
__global__ __launch_bounds__(256) void pos_kernel(
    const float* __restrict__ Worig, float* __restrict__ W,
    const float* __restrict__ lut,
    const int* __restrict__ idx_u, const int* __restrict__ idx_v, int n)
{
    int wave = (int)((blockIdx.x * blockDim.x + threadIdx.x) >> 6);
    int lane = threadIdx.x & 63;
    if (wave >= n) return;
    int u = idx_u[wave];
    int v = idx_v[wave];
    float2 eu = ((const float2*)(Worig + (size_t)u * D))[lane];
    float2 ev = ((const float2*)(Worig + (size_t)v * D))[lane];
    float dot = wave_allreduce(eu.x * ev.x + eu.y * ev.y);
    float s = (1.0f - fast_sig_lut(dot - NCE_BIAS, lut)) * LR;
    float* wu = W + (size_t)u * D;
    float* wv = W + (size_t)v * D;
    atomicAdd(&wu[2 * lane],     s * ev.x);
    atomicAdd(&wu[2 * lane + 1], s * ev.y);
    atomicAdd(&wv[2 * lane],     s * eu.x);
    atomicAdd(&wv[2 * lane + 1], s * eu.y);
}

__global__ __launch_bounds__(256) void neg_kernel(
    const float* __restrict__ Wsnap, float* __restrict__ W,
    const float* __restrict__ lut,
    const int* __restrict__ idx_u, const int* __restrict__ idx_v, int n, int neg)
{
    int wave = (int)((blockIdx.x * blockDim.x + threadIdx.x) >> 6);
    int lane = threadIdx.x & 63;
    if (wave >= n) return;
    int u = idx_u[wave * neg];
    float2 eu = ((const float2*)(Wsnap + (size_t)u * D))[lane];
    float dux = 0.0f, duy = 0.0f;
    for (int j = 0; j < neg; ++j) {
        int v = idx_v[wave * neg + j];
        float2 ev = ((const float2*)(Wsnap + (size_t)v * D))[lane];
        float dot = wave_allreduce(eu.x * ev.x + eu.y * ev.y);
        float s = -fast_sig_lut(dot - NCE_NEG_BIAS, lut) * LR;
        dux += s * ev.x;
        duy += s * ev.y;
        float* wv = W + (size_t)v * D;
        atomicAdd(&wv[2 * lane],     s * eu.x);
        atomicAdd(&wv[2 * lane + 1], s * eu.y);
    }
    float* wu = W + (size_t)u * D;
    atomicAdd(&wu[2 * lane],     dux);
    atomicAdd(&wu[2 * lane + 1], duy);
}

extern "C" void kernel_launch(void* const* d_in, const int* in_sizes, int n_in,
                              void* d_out, int out_size, void* d_ws, size_t ws_size,
                              hipStream_t stream) {
    const float* W   = (const float*)d_in[0];
    const float* lut = (const float*)d_in[1];
    const int* ipu   = (const int*)d_in[2];
    const int* ipv   = (const int*)d_in[3];
    const int* inu   = (const int*)d_in[4];
    const int* inv   = (const int*)d_in[5];
    float* out = (float*)d_out;

    const int N  = in_sizes[0] / D;        // nodes
    const int Np = in_sizes[2];            // positive pairs
    const int Nn = in_sizes[4];            // negative pairs (N*NEG)
    const int NEG = Nn / Np;
    const size_t WB = (size_t)N * D * sizeof(float);
    const int nb = (N + 255) / 256;
    const int n_entp = 2 * Np;
    const int n_entn = NEG * Np + Nn;

    size_t need = (size_t)N * D * 2                   // ws16 bf16 shadow
                + (size_t)n_entp * 4 + (size_t)n_entn * 4
                + (size_t)N * 4 * 5                   // cnt, off_p, off_n, cur_p, cur_n
                + (size_t)nb * 4 * 2 + 64;

    if (ws_size >= need) {
        char* p = (char*)d_ws;
        unsigned short* ws16 = (unsigned short*)p; p += (size_t)N * D * 2;
        int* ent_p = (int*)p; p += (size_t)n_entp * 4;
        int* ent_n = (int*)p; p += (size_t)n_entn * 4;
        int* cnt   = (int*)p; p += (size_t)N * 4;
        int* off_p = (int*)p; p += (size_t)N * 4;
        int* off_n = (int*)p; p += (size_t)N * 4;
        int* cur_p = (int*)p; p += (size_t)N * 4;
        int* cur_n = (int*)p; p += (size_t)N * 4;
        int* bsA   = (int*)p; p += (size_t)nb * 4;
        int* bsB   = (int*)p;

        hipMemsetAsync(cnt, 0, (size_t)N * 4, stream);
        int tot = Np + Nn;
        hist_kernel <<<(tot + 255) / 256, 256, 0, stream>>>(ipu, ipv, inu, inv, Np, Nn, NEG, cnt);
        hist_kernel2<<<(Np + 255) / 256, 256, 0, stream>>>(ipv, Np, cnt);
        scan_local<<<nb, 256, 0, stream>>>(cnt, off_p, bsA, N, 0);
        scan_bsum<<<1, 256, 0, stream>>>(bsA, nb);
        add_base<<<nb, 256, 0, stream>>>(off_p, cur_p, bsA, N);
        scan_local<<<nb, 256, 0, stream>>>(cnt, off_n, bsB, N, 16);
        scan_bsum<<<1, 256, 0, stream>>>(bsB, nb);
        add_base<<<nb, 256, 0, stream>>>(off_n, cur_n, bsB, N);
        fill_kernel<<<(tot + 255) / 256, 256, 0, stream>>>(ipu, ipv, inu, inv, Np, Nn, NEG,
                                                           cur_p, cur_n, ent_p, ent_n);

        int ublocks = (N * 32 + 255) / 256;
        // pos: base=W, partners=W fp32; write Wpos fp32 -> d_out AND bf16 shadow -> ws16
        update_kernel<false, true><<<ublocks, 256, 0, stream>>>(
            W, W, (const unsigned short*)nullptr, out, ws16,
            off_p, cur_p, ent_p, N, NCE_BIAS, 1.0f);
        // neg: base=own row of d_out (fp32 Wpos), partners=ws16 bf16; overwrite own row of d_out
        update_kernel<true, false><<<ublocks, 256, 0, stream>>>(
            out, (const float*)nullptr, ws16, out, (unsigned short*)nullptr,
            off_n, cur_n, ent_n, N, NCE_NEG_BIAS, 0.0f);
    } else {
        // scatter fallback (needs only one W-sized snapshot)
        float* snap = (float*)d_ws;
        hipMemcpyAsync(out, W, WB, hipMemcpyDeviceToDevice, stream);
        int blocks = (Np * 64 + 255) / 256;
        pos_kernel<<<blocks, 256, 0, stream>>>(W, out, lut, ipu, ipv, Np);
        hipMemcpyAsync(snap, out, WB, hipMemcpyDeviceToDevice, stream);
        neg_kernel<<<blocks, 256, 0, stream>>>(snap, out, lut, inu, inv, Np, NEG);
    }
}

// Round 6
// 272.385 us; speedup vs baseline: 2.8524x; 1.1471x over previous
//
#include <hip/hip_runtime.h>
#include <hip/hip_bf16.h>

#define D 128
#define LR 0.025f
#define NCE_BIAS 11.512925464970229f      // log(100000)
#define NCE_NEG_BIAS 9.903487552536127f   // log(100000/5)
#define LUT_SIZE 1202

__device__ __forceinline__ float wave_allreduce(float x) {
    #pragma unroll
    for (int m = 32; m >= 1; m >>= 1) x += __shfl_xor(x, m, 64);
    return x;
}

// Analytic stand-in for the reference's LUT sigmoid (centered quantization err <=1.25e-3).
__device__ __forceinline__ float fast_sig(float x) {
    x = fminf(fmaxf(x, -6.0f), 6.0f) - 0.005f;
    float e = __expf(-x);
    return __builtin_amdgcn_rcpf(1.0f + e);
}

__device__ __forceinline__ float fast_sig_lut(float s, const float* __restrict__ lut) {
    s = fminf(fmaxf(s, -6.0f), 6.0f);
    int idx = (int)floorf((s + 6.01f) / 0.01f);
    idx = min(max(idx, 0), LUT_SIZE - 1);
    return lut[idx];
}

__device__ __forceinline__ unsigned int bf16_rne(float f) {
    unsigned int u = __float_as_uint(f);
    return (u + 0x7FFFu + ((u >> 16) & 1u)) >> 16;
}

// ---------------- W -> bf16 shadow ----------------
__global__ __launch_bounds__(256) void conv_kernel(
    const float* __restrict__ W, unsigned short* __restrict__ w16, int n32)
{
    int g = blockIdx.x * 256 + threadIdx.x;
    if (g >= n32) return;
    float4 v = ((const float4*)W)[g];
    uint2 h;
    h.x = bf16_rne(v.x) | (bf16_rne(v.y) << 16);
    h.y = bf16_rne(v.z) | (bf16_rne(v.w) << 16);
    ((uint2*)w16)[g] = h;
}

// ---------------- CSR build ----------------
// cnt2[i] = {pos_degree, neg_degree}. Pos pair t: ONE 64-bit atomic bumps both
// fields of u (pos +1, neg +NEG — idx_neg_u = repeat(idx_pos_u, NEG)).
__global__ __launch_bounds__(256) void hist_kernel(
    const int* __restrict__ ipu, const int* __restrict__ ipv,
    const int* __restrict__ inv,
    int Np, int Nn, int NEG, int2* __restrict__ cnt2)
{
    int t = blockIdx.x * 256 + threadIdx.x;
    if (t < Np) {
        atomicAdd((unsigned long long*)&cnt2[ipu[t]],
                  1ull + ((unsigned long long)NEG << 32));
        atomicAdd(&cnt2[ipv[t]].x, 1);
    } else if (t < Np + Nn) {
        int k = t - Np;
        atomicAdd(&cnt2[inv[k]].y, 1);
    }
}

// fused dual exclusive scan (pos & neg fields in one pass)
__global__ __launch_bounds__(256) void scan_local2(
    const int2* __restrict__ cnt2, int* __restrict__ off_p, int* __restrict__ off_n,
    int* __restrict__ bsp, int* __restrict__ bsn, int n)
{
    __shared__ int shp[256], shn[256];
    int g = blockIdx.x * 256 + threadIdx.x;
    int2 x = (g < n) ? cnt2[g] : make_int2(0, 0);
    shp[threadIdx.x] = x.x;
    shn[threadIdx.x] = x.y;
    __syncthreads();
    #pragma unroll
    for (int d = 1; d < 256; d <<= 1) {
        int tp = (threadIdx.x >= d) ? shp[threadIdx.x - d] : 0;
        int tn = (threadIdx.x >= d) ? shn[threadIdx.x - d] : 0;
        __syncthreads();
        shp[threadIdx.x] += tp;
        shn[threadIdx.x] += tn;
        __syncthreads();
    }
    if (g < n) {
        off_p[g] = shp[threadIdx.x] - x.x;
        off_n[g] = shn[threadIdx.x] - x.y;
    }
    if (threadIdx.x == 255) {
        bsp[blockIdx.x] = shp[255];
        bsn[blockIdx.x] = shn[255];
    }
}

__device__ __forceinline__ void scan_one(int* b, int nb) {
    __shared__ int sh[256];
    __shared__ int carry_s;
    if (threadIdx.x == 0) carry_s = 0;
    __syncthreads();
    for (int c = 0; c < nb; c += 256) {
        int i = c + threadIdx.x;
        int x = (i < nb) ? b[i] : 0;
        sh[threadIdx.x] = x;
        __syncthreads();
        for (int d = 1; d < 256; d <<= 1) {
            int t = (threadIdx.x >= d) ? sh[threadIdx.x - d] : 0;
            __syncthreads();
            sh[threadIdx.x] += t;
            __syncthreads();
        }
        int carry = carry_s;
        if (i < nb) b[i] = sh[threadIdx.x] - x + carry;
        __syncthreads();
        if (threadIdx.x == 0) carry_s = carry + sh[255];
        __syncthreads();
    }
}

__global__ __launch_bounds__(256) void scan_bsum2(int* __restrict__ bsp, int* __restrict__ bsn, int nb)
{
    scan_one(bsp, nb);
    __syncthreads();
    scan_one(bsn, nb);
}

__global__ __launch_bounds__(256) void add_base2(
    int* __restrict__ off_p, int* __restrict__ off_n, int2* __restrict__ cur2,
    const int* __restrict__ bsp, const int* __restrict__ bsn, int n)
{
    int g = blockIdx.x * 256 + threadIdx.x;
    if (g < n) {
        int vp = off_p[g] + bsp[blockIdx.x];
        int vn = off_n[g] + bsn[blockIdx.x];
        off_p[g] = vp;
        off_n[g] = vn;
        cur2[g] = make_int2(vp, vn);
    }
}

// pos pair t: ONE 64-bit atomic reserves the u-side pos slot AND NEG contiguous
// neg slots; neg partners written contiguously.
__global__ __launch_bounds__(256) void fill_kernel(
    const int* __restrict__ ipu, const int* __restrict__ ipv,
    const int* __restrict__ inu, const int* __restrict__ inv,
    int Np, int Nn, int NEG,
    int2* __restrict__ cur2, int* __restrict__ ent_p, int* __restrict__ ent_n)
{
    int t = blockIdx.x * 256 + threadIdx.x;
    if (t < Np) {
        int u = ipu[t], v = ipv[t];
        unsigned long long pk = atomicAdd((unsigned long long*)&cur2[u],
                                          1ull + ((unsigned long long)NEG << 32));
        int slot_pu = (int)(pk & 0xFFFFFFFFull);
        int slot_nu = (int)(pk >> 32);
        ent_p[slot_pu] = v;
        for (int j = 0; j < NEG; ++j)
            ent_n[slot_nu + j] = inv[(size_t)NEG * t + j];
        ent_p[atomicAdd(&cur2[v].x, 1)] = u;
    } else if (t < Np + Nn) {
        int k = t - Np;
        ent_n[atomicAdd(&cur2[inv[k]].y, 1)] = inu[k];
    }
}

// ---------------- pull update (software-pipelined) ----------------
// Half-wave per node (32 lanes x float4 base). Partners are bf16 (256B rows).
// Entries prefetched 2 groups ahead; partner rows 1 group ahead (8 loads in flight).
template<bool EMIT16>
__global__ __launch_bounds__(256) void update_kernel(
    const float* __restrict__ baseSrc,
    const unsigned short* __restrict__ partnerH,
    float* __restrict__ dst, unsigned short* __restrict__ dst16,
    const int* __restrict__ offArr, const int* __restrict__ endArr2, int comp,
    const int* __restrict__ entries, int N, float bias, float cpos)
{
    int gtid = blockIdx.x * 256 + threadIdx.x;
    int node = gtid >> 5;
    int hl   = threadIdx.x & 31;
    if (node >= N) return;

    float4 base = ((const float4*)baseSrc)[(size_t)node * 32 + hl];
    float ax = 0.0f, ay = 0.0f, az = 0.0f, aw = 0.0f;

    int beg = offArr[node];
    int len = endArr2[2 * node + comp] - beg;
    const uint2* ph = (const uint2*)partnerH;

    if (len > 0) {
        int gcount = (len + 3) >> 2;
        int en[4];
        uint2 rc[4];
        #pragma unroll
        for (int i = 0; i < 4; ++i) {
            int t = min(i, len - 1);
            rc[i] = ph[(size_t)entries[beg + t] * 32 + hl];
        }
        #pragma unroll
        for (int i = 0; i < 4; ++i) {
            int t = min(4 + i, len - 1);
            en[i] = entries[beg + t];
        }
        for (int g = 0; g < gcount; ++g) {
            uint2 rn[4];
            #pragma unroll
            for (int i = 0; i < 4; ++i) rn[i] = ph[(size_t)en[i] * 32 + hl];
            int en2[4];
            #pragma unroll
            for (int i = 0; i < 4; ++i) {
                int t = (g + 2) * 4 + i;
                t = (t < len) ? t : (len - 1);
                en2[i] = entries[beg + t];
            }
            float4 r[4];
            float d[4];
            #pragma unroll
            for (int i = 0; i < 4; ++i) {
                r[i].x = __uint_as_float(rc[i].x << 16);
                r[i].y = __uint_as_float(rc[i].x & 0xFFFF0000u);
                r[i].z = __uint_as_float(rc[i].y << 16);
                r[i].w = __uint_as_float(rc[i].y & 0xFFFF0000u);
                d[i] = r[i].x * base.x + r[i].y * base.y + r[i].z * base.z + r[i].w * base.w;
            }
            #pragma unroll
            for (int m = 16; m >= 1; m >>= 1) {
                #pragma unroll
                for (int i = 0; i < 4; ++i) d[i] += __shfl_xor(d[i], m, 64);
            }
            #pragma unroll
            for (int i = 0; i < 4; ++i) {
                float s = (g * 4 + i < len) ? (cpos - fast_sig(d[i] - bias)) * LR : 0.0f;
                ax += s * r[i].x;
                ay += s * r[i].y;
                az += s * r[i].z;
                aw += s * r[i].w;
            }
            #pragma unroll
            for (int i = 0; i < 4; ++i) { rc[i] = rn[i]; en[i] = en2[i]; }
        }
    }
    float4 o = make_float4(base.x + ax, base.y + ay, base.z + az, base.w + aw);
    ((float4*)dst)[(size_t)node * 32 + hl] = o;
    if (EMIT16) {
        uint2 h;
        h.x = bf16_rne(o.x) | (bf16_rne(o.y) << 16);
        h.y = bf16_rne(o.z) | (bf16_rne(o.w) << 16);
        ((uint2*)dst16)[(size_t)node * 32 + hl] = h;
    }
}

// ---------------- fallback scatter path (round-1, known-good) ----------------
__global__ __launch_bounds__(256) void pos_kernel(
    const float* __restrict__ Worig, float* __restrict__ W,
    const float* __restrict__ lut,
    const int* __restrict__ idx_u, const int* __restrict__ idx_v, int n)
{
    int wave = (int)((blockIdx.x * blockDim.x + threadIdx.x) >> 6);
    int lane = threadIdx.x & 63;
    if (wave >= n) return;
    int u = idx_u[wave];
    int v = idx_v[wave];
    float2 eu = ((const float2*)(Worig + (size_t)u * D))[lane];
    float2 ev = ((const float2*)(Worig + (size_t)v * D))[lane];
    float dot = wave_allreduce(eu.x * ev.x + eu.y * ev.y);
    float s = (1.0f - fast_sig_lut(dot - NCE_BIAS, lut)) * LR;
    float* wu = W + (size_t)u * D;
    float* wv = W + (size_t)v * D;
    atomicAdd(&wu[2 * lane],     s * ev.x);
    atomicAdd(&wu[2 * lane + 1], s * ev.y);
    atomicAdd(&wv[2 * lane],     s * eu.x);
    atomicAdd(&wv[2 * lane + 1], s * eu.y);
}

__global__ __launch_bounds__(256) void neg_kernel(
    const float* __restrict__ Wsnap, float* __restrict__ W,
    const float* __restrict__ lut,
    const int* __restrict__ idx_u, const int* __restrict__ idx_v, int n, int neg)
{
    int wave = (int)((blockIdx.x * blockDim.x + threadIdx.x) >> 6);
    int lane = threadIdx.x & 63;
    if (wave >= n) return;
    int u = idx_u[wave * neg];
    float2 eu = ((const float2*)(Wsnap + (size_t)u * D))[lane];
    float dux = 0.0f, duy = 0.0f;
    for (int j = 0; j < neg; ++j) {
        int v = idx_v[wave * neg + j];
        float2 ev = ((const float2*)(Wsnap + (size_t)v * D))[lane];
        float dot = wave_allreduce(eu.x * ev.x + eu.y * ev.y);
        float s = -fast_sig_lut(dot - NCE_NEG_BIAS, lut) * LR;
        dux += s * ev.x;
        duy += s * ev.y;
        float* wv = W + (size_t)v * D;
        atomicAdd(&wv[2 * lane],     s * eu.x);
        atomicAdd(&wv[2 * lane + 1], s * eu.y);
    }
    float* wu = W + (size_t)u * D;
    atomicAdd(&wu[2 * lane],     dux);
    atomicAdd(&wu[2 * lane + 1], duy);
}

extern "C" void kernel_launch(void* const* d_in, const int* in_sizes, int n_in,
                              void* d_out, int out_size, void* d_ws, size_t ws_size,
                              hipStream_t stream) {
    const float* W   = (const float*)d_in[0];
    const float* lut = (const float*)d_in[1];
    const int* ipu   = (const int*)d_in[2];
    const int* ipv   = (const int*)d_in[3];
    const int* inu   = (const int*)d_in[4];
    const int* inv   = (const int*)d_in[5];
    float* out = (float*)d_out;

    const int N  = in_sizes[0] / D;        // nodes
    const int Np = in_sizes[2];            // positive pairs
    const int Nn = in_sizes[4];            // negative pairs (N*NEG)
    const int NEG = Nn / Np;
    const size_t WB = (size_t)N * D * sizeof(float);
    const int nb = (N + 255) / 256;
    const int n_entp = 2 * Np;
    const int n_entn = NEG * Np + Nn;

    size_t need = (size_t)N * D * 2 * 2                       // w16W + w16P
                + (size_t)n_entp * 4 + (size_t)n_entn * 4
                + (size_t)N * 8 * 2 + (size_t)N * 4 * 2       // cnt2, cur2, off_p, off_n
                + (size_t)nb * 4 * 2 + 64;

    if (ws_size >= need) {
        char* p = (char*)d_ws;
        unsigned short* w16W = (unsigned short*)p; p += (size_t)N * D * 2;
        unsigned short* w16P = (unsigned short*)p; p += (size_t)N * D * 2;
        int*  ent_p = (int*)p;  p += (size_t)n_entp * 4;
        int*  ent_n = (int*)p;  p += (size_t)n_entn * 4;
        int2* cnt2  = (int2*)p; p += (size_t)N * 8;
        int2* cur2  = (int2*)p; p += (size_t)N * 8;
        int*  off_p = (int*)p;  p += (size_t)N * 4;
        int*  off_n = (int*)p;  p += (size_t)N * 4;
        int*  bsp   = (int*)p;  p += (size_t)nb * 4;
        int*  bsn   = (int*)p;

        hipMemsetAsync(cnt2, 0, (size_t)N * 8, stream);
        int n32 = N * 32;
        conv_kernel<<<(n32 + 255) / 256, 256, 0, stream>>>(W, w16W, n32);
        int tot = Np + Nn;
        hist_kernel<<<(tot + 255) / 256, 256, 0, stream>>>(ipu, ipv, inv, Np, Nn, NEG, cnt2);
        scan_local2<<<nb, 256, 0, stream>>>(cnt2, off_p, off_n, bsp, bsn, N);
        scan_bsum2<<<1, 256, 0, stream>>>(bsp, bsn, nb);
        add_base2<<<nb, 256, 0, stream>>>(off_p, off_n, cur2, bsp, bsn, N);
        fill_kernel<<<(tot + 255) / 256, 256, 0, stream>>>(ipu, ipv, inu, inv, Np, Nn, NEG,
                                                           cur2, ent_p, ent_n);

        int ublocks = (n32 + 255) / 256;
        // pos: base=W fp32, partners=bf16(W); write Wpos fp32 -> d_out + bf16 shadow -> w16P
        update_kernel<true><<<ublocks, 256, 0, stream>>>(
            W, w16W, out, w16P, off_p, (const int*)cur2, 0, ent_p, N, NCE_BIAS, 1.0f);
        // neg: base=own fp32 row of d_out (Wpos), partners=bf16(Wpos); overwrite own row
        update_kernel<false><<<ublocks, 256, 0, stream>>>(
            out, w16P, out, (unsigned short*)nullptr, off_n, (const int*)cur2, 1, ent_n,
            N, NCE_NEG_BIAS, 0.0f);
    } else {
        // scatter fallback (needs only one W-sized snapshot)
        float* snap = (float*)d_ws;
        hipMemcpyAsync(out, W, WB, hipMemcpyDeviceToDevice, stream);
        int blocks = (Np * 64 + 255) / 256;
        pos_kernel<<<blocks, 256, 0, stream>>>(W, out, lut, ipu, ipv, Np);
        hipMemcpyAsync(snap, out, WB, hipMemcpyDeviceToDevice, stream);
        neg_kernel<<<blocks, 256, 0, stream>>>(snap, out, lut, inu, inv, Np, NEG);
    }
}